// Round 10
// baseline (211.956 us; speedup 1.0000x reference)
//
#include <hip/hip_runtime.h>
#include <math.h>

#define NQ     2048
#define DMODEL 512
#define NH     8
#define DHD    64
#define MEMT   512
#define KVT    2560
#define QSCALE 0.125f
#define NEGF   (-1e30f)

typedef unsigned short u16;
typedef __bf16 bf16x8 __attribute__((ext_vector_type(8)));
typedef float  f32x4  __attribute__((ext_vector_type(4)));
typedef u16    u16x8  __attribute__((ext_vector_type(8)));
typedef u16    u16x4  __attribute__((ext_vector_type(4)));
typedef u16    u16x2  __attribute__((ext_vector_type(2)));

__device__ __forceinline__ u16 f2bf(float f) {
    union { float f; unsigned u; } v; v.f = f;
    unsigned r = (v.u + 0x7FFFu + ((v.u >> 16) & 1u)) >> 16;
    return (u16)r;
}

// ---------------------------------------------------------------------------
// prep: [0,32) x->bf16 | [32,288) W transposes | [288,320) gates
//       [320,384) RoPE table | [384,448) cache-V transpose | [448,512) cache-K RoPE
// ---------------------------------------------------------------------------
__global__ __launch_bounds__(256, 4) void prep(const float* __restrict__ x,
                                               const float* __restrict__ Wq,
                                               const float* __restrict__ Wkv,
                                               const float* __restrict__ Wo,
                                               const float* __restrict__ Wg,
                                               const float* __restrict__ cache_v,
                                               const float* __restrict__ cache_k,
                                               u16* __restrict__ xb,
                                               u16* __restrict__ Wt,
                                               u16* __restrict__ Wot,
                                               float* __restrict__ gates,
                                               float2* __restrict__ cs,
                                               u16* __restrict__ vtb,
                                               u16* __restrict__ kb) {
    __shared__ __attribute__((aligned(16))) char smem[16640];
    int bid = blockIdx.x, tid = threadIdx.x;

    if (bid < 32) {                          // x -> bf16
        int base4 = bid * 8192;
#pragma unroll
        for (int u = 0; u < 32; ++u) {
            int i4 = base4 + u * 256 + tid;
            float4 v = ((const float4*)x)[i4];
            u16x4 o4 = { f2bf(v.x), f2bf(v.y), f2bf(v.z), f2bf(v.w) };
            *(u16x4*)&xb[i4 * 4] = o4;
        }
    } else if (bid < 288) {                  // W transposes
        float (*tile)[65] = (float(*)[65])smem;
        int tt = bid - 32;
        bool isQKV = (tt < 192);
        int tc, tr;
        if (isQKV) { tc = tt % 24; tr = tt / 24; }
        else       { tt -= 192; tc = tt & 7; tr = tt >> 3; }
        int rr = tid >> 4, c4 = (tid & 15) * 4;
#pragma unroll
        for (int u = 0; u < 4; ++u) {
            int row = u * 16 + rr;
            int k = tr * 64 + row, c = tc * 64 + c4;
            float4 v;
            if (isQKV) v = (c < 512) ? *(const float4*)&Wq[k * 512 + c]
                                     : *(const float4*)&Wkv[k * 1024 + (c - 512)];
            else       v = *(const float4*)&Wo[k * 512 + c];
            tile[row][c4 + 0] = v.x; tile[row][c4 + 1] = v.y;
            tile[row][c4 + 2] = v.z; tile[row][c4 + 3] = v.w;
        }
        __syncthreads();
#pragma unroll
        for (int u = 0; u < 4; ++u) {
            int trow = u * 16 + rr;
            u16x4 o4;
#pragma unroll
            for (int i = 0; i < 4; ++i) o4[i] = f2bf(tile[c4 + i][trow]);
            int tg = tc * 64 + trow, kg = tr * 64 + c4;
            if (isQKV) *(u16x4*)&Wt[tg * 512 + kg] = o4;
            else       *(u16x4*)&Wot[tg * 512 + kg] = o4;
        }
    } else if (bid < 320) {                  // gates
#pragma unroll
        for (int kk = 0; kk < 2; ++kk) {
            int t = (bid - 288) * 512 + kk * 256 + tid;
            int n = t >> 3, hh = t & 7;
            float acc = 0.f;
            for (int k = 0; k < DMODEL; k += 4) {
                float4 xv = *(const float4*)&x[n * DMODEL + k];
                acc += xv.x * Wg[(k + 0) * NH + hh] + xv.y * Wg[(k + 1) * NH + hh]
                     + xv.z * Wg[(k + 2) * NH + hh] + xv.w * Wg[(k + 3) * NH + hh];
            }
            gates[hh * NQ + n] = 1.f / (1.f + __expf(-acc));
        }
    } else if (bid < 384) {                  // RoPE cos/sin table (for qkv epilogue)
#pragma unroll
        for (int kk = 0; kk < 5; ++kk) {
            int idx = (bid - 320) * 1280 + kk * 256 + tid;
            int pos = idx >> 5, j = idx & 31;
            float invf = exp2f(-(float)j * (13.287712379549449f / 32.f));
            float ss, sc;
            sincosf((float)pos * invf, &ss, &sc);
            cs[idx] = make_float2(sc, ss);
        }
    } else if (bid < 448) {                  // cache-V transpose -> vtb rows [0,512)
        u16 (*tile)[66] = (u16(*)[66])smem;
        int uu = bid - 384;
        int tb = uu & 7, h = uu >> 3;
        int rr = tid >> 4, c4 = (tid & 15) * 4;
        int r0 = tb * 64;
#pragma unroll
        for (int u = 0; u < 4; ++u) {
            int row = u * 16 + rr;
            float4 v = *(const float4*)&cache_v[(h * MEMT + r0 + row) * DHD + c4];
            tile[row][c4 + 0] = f2bf(v.x); tile[row][c4 + 1] = f2bf(v.y);
            tile[row][c4 + 2] = f2bf(v.z); tile[row][c4 + 3] = f2bf(v.w);
        }
        __syncthreads();
#pragma unroll
        for (int u = 0; u < 4; ++u) {
            int d = u * 16 + rr;
            u16x4 o4 = { tile[c4 + 0][d], tile[c4 + 1][d], tile[c4 + 2][d], tile[c4 + 3][d] };
            *(u16x4*)&vtb[(h * DHD + d) * KVT + r0 + c4] = o4;
        }
    } else {                                 // cache-K RoPE (inline sincos) -> kb [0,512)
        int uu = bid - 448;
        int r0 = (uu & 7) * 64, h = uu >> 3;
        int j = tid & 31;
        float invf = exp2f(-(float)j * (13.287712379549449f / 32.f));
#pragma unroll
        for (int u = 0; u < 8; ++u) {
            int idx = u * 256 + tid;
            int row = idx >> 5;
            int r = r0 + row;
            float a = cache_k[(h * MEMT + r) * DHD + j];
            float b = cache_k[(h * MEMT + r) * DHD + 32 + j];
            float ss, sc;
            sincosf((float)r * invf, &ss, &sc);
            kb[(h * KVT + r) * DHD + j]      = f2bf(a * sc - b * ss);
            kb[(h * KVT + r) * DHD + 32 + j] = f2bf(b * sc + a * ss);
        }
    }
}

// ---------------------------------------------------------------------------
// qkv: 1536 blocks, one 32x64 tile each (XCD-swizzled: xcd owns 3 col-panels).
// Epilogue: RoPE (q/k) via cs table, V transposed via LDS into vtb.
// ---------------------------------------------------------------------------
__global__ __launch_bounds__(256, 4) void qkv(const u16* __restrict__ xb,
                                              const u16* __restrict__ Wt,
                                              const float2* __restrict__ cs,
                                              u16* __restrict__ qb,
                                              u16* __restrict__ kb,
                                              u16* __restrict__ vtb) {
    __shared__ __attribute__((aligned(16))) u16 vtile[32][66];
    const int bid = blockIdx.x, tid = threadIdx.x;
    const int w = tid >> 6, lane = tid & 63;
    const int lr = lane & 15, lg = lane >> 4;

    int i = bid >> 3;                        // 0..191
    int sub = i % 3, byr = i / 3;            // col-in-triple, row tile 0..63
    int bx = (bid & 7) * 3 + sub;            // col panel 0..23, XCD-local triple
    int rowbase = byr * 32;
    int rfrag = rowbase + (w >> 1) * 16;
    int colbase = bx * 64 + (w & 1) * 16;

    f32x4 acc0 = {0.f,0.f,0.f,0.f}, acc1 = {0.f,0.f,0.f,0.f};
    const u16* a0 = xb + (rfrag + lr) * 512 + lg * 8;
    const u16* b0 = Wt + (colbase + lr) * 512 + lg * 8;
    const u16* b1 = b0 + 32 * 512;
#pragma unroll 4
    for (int k0 = 0; k0 < 512; k0 += 32) {
        bf16x8 fa  = __builtin_bit_cast(bf16x8, *(const u16x8*)(a0 + k0));
        bf16x8 fb0 = __builtin_bit_cast(bf16x8, *(const u16x8*)(b0 + k0));
        bf16x8 fb1 = __builtin_bit_cast(bf16x8, *(const u16x8*)(b1 + k0));
        acc0 = __builtin_amdgcn_mfma_f32_16x16x32_bf16(fa, fb0, acc0, 0, 0, 0);
        acc1 = __builtin_amdgcn_mfma_f32_16x16x32_bf16(fa, fb1, acc1, 0, 0, 0);
    }

    int j = (colbase & 63) + lr;             // 0..31
    int region = bx >> 3;                    // 0=q, 1=k_new, 2=v
    int h = bx & 7;
    if (region == 2) {
        __syncthreads();
#pragma unroll
        for (int r = 0; r < 4; ++r) {
            int rl = (w >> 1) * 16 + lg * 4 + r;
            vtile[rl][j]      = f2bf(acc0[r]);
            vtile[rl][j + 32] = f2bf(acc1[r]);
        }
        __syncthreads();
        int rr = tid >> 4, c2 = (tid & 15) * 2;
#pragma unroll
        for (int u = 0; u < 4; ++u) {
            int d = u * 16 + rr;
            u16x2 o2 = { vtile[c2][d], vtile[c2 + 1][d] };
            *(u16x2*)&vtb[(h * DHD + d) * KVT + 512 + rowbase + c2] = o2;
        }
    } else {
#pragma unroll
        for (int r = 0; r < 4; ++r) {
            int n = rfrag + lg * 4 + r;
            float a = acc0[r], b = acc1[r];
            float2 csv = cs[(512 + n) * 32 + j];
            u16 e0 = f2bf(a * csv.x - b * csv.y);
            u16 e1 = f2bf(b * csv.x + a * csv.y);
            if (region == 0) {
                qb[(h * NQ + n) * DHD + j]      = e0;
                qb[(h * NQ + n) * DHD + 32 + j] = e1;
            } else {
                kb[(h * KVT + 512 + n) * DHD + j]      = e0;
                kb[(h * KVT + 512 + n) * DHD + 32 + j] = e1;
            }
        }
    }
}

// ---------------------------------------------------------------------------
// attn: 1024 blocks = (head = bid&7, 16-query tile = bid>>3). 4 waves each own
// a quarter of the KV chunks (online softmax per wave), 4-way merge via LDS.
// ---------------------------------------------------------------------------
#define LOADK(BK, BEP, C0)                                                     \
  _Pragma("unroll")                                                            \
  for (int t = 0; t < 4; ++t) {                                                \
    const u16* kr = kb + ((h * KVT + (C0) + t * 16 + lr) * DHD + lg * 8);      \
    BK[t][0] = __builtin_bit_cast(bf16x8, *(const u16x8*)kr);                  \
    BK[t][1] = __builtin_bit_cast(bf16x8, *(const u16x8*)(kr + 32));           \
    BEP[t] = ep[(C0) + t * 16 + lr];                                           \
  }

#define DO_CHUNK(C0, BK, BEP, PREF, NBK, NBEP)                                 \
  {                                                                            \
    bf16x8 bV[4][2];                                                           \
    _Pragma("unroll")                                                          \
    for (int t = 0; t < 4; ++t) {                                              \
      const u16* vr = vtb + ((h * DHD + t * 16 + lr) * KVT + (C0) + lg * 8);   \
      bV[t][0] = __builtin_bit_cast(bf16x8, *(const u16x8*)vr);                \
      bV[t][1] = __builtin_bit_cast(bf16x8, *(const u16x8*)(vr + 32));         \
    }                                                                          \
    f32x4 s[4];                                                                \
    _Pragma("unroll")                                                          \
    for (int t = 0; t < 4; ++t) {                                              \
      f32x4 z = {0.f, 0.f, 0.f, 0.f};                                          \
      s[t] = __builtin_amdgcn_mfma_f32_16x16x32_bf16(aQ[0], BK[t][0], z, 0, 0, 0); \
      s[t] = __builtin_amdgcn_mfma_f32_16x16x32_bf16(aQ[1], BK[t][1], s[t], 0, 0, 0); \
    }                                                                          \
    if (PREF) { LOADK(NBK, NBEP, (C0) + 64) }                                  \
    float rmax[4] = {NEGF, NEGF, NEGF, NEGF};                                  \
    _Pragma("unroll")                                                          \
    for (int t = 0; t < 4; ++t) {                                              \
      int key = (C0) + t * 16 + lr;                                            \
      int ek = BEP[t];                                                         \
      _Pragma("unroll")                                                        \
      for (int r = 0; r < 4; ++r) {                                            \
        bool vld = (key <= qpos[r]) && (ek == epq[r]);                         \
        float sv = vld ? s[t][r] * QSCALE : NEGF;                              \
        s[t][r] = sv;                                                          \
        rmax[r] = fmaxf(rmax[r], sv);                                          \
      }                                                                        \
    }                                                                          \
    _Pragma("unroll")                                                          \
    for (int mm = 1; mm < 16; mm <<= 1) {                                      \
      _Pragma("unroll")                                                        \
      for (int r = 0; r < 4; ++r)                                              \
        rmax[r] = fmaxf(rmax[r], __shfl_xor(rmax[r], mm, 64));                 \
    }                                                                          \
    float alpha[4];                                                            \
    _Pragma("unroll")                                                          \
    for (int r = 0; r < 4; ++r) {                                              \
      float mn = fmaxf(mrun[r], rmax[r]);                                      \
      alpha[r] = __expf(mrun[r] - mn);                                         \
      mrun[r] = mn;                                                            \
      lsum[r] *= alpha[r];                                                     \
    }                                                                          \
    _Pragma("unroll")                                                          \
    for (int t = 0; t < 4; ++t)                                                \
      _Pragma("unroll")                                                        \
      for (int r = 0; r < 4; ++r) o[t][r] *= alpha[r];                         \
    float psum[4] = {0.f, 0.f, 0.f, 0.f};                                      \
    _Pragma("unroll")                                                          \
    for (int t = 0; t < 4; ++t) {                                              \
      _Pragma("unroll")                                                        \
      for (int r = 0; r < 4; ++r) {                                            \
        float sv = s[t][r];                                                    \
        float p = (sv <= -1e29f) ? 0.f : __expf(sv - mrun[r]);                 \
        psum[r] += p;                                                          \
        int qq = lg * 4 + r;                                                   \
        int kk2 = t * 16 + lr;                                                 \
        pl[qq * 64 + (kk2 ^ ((qq & 7) << 3))] = f2bf(p);                       \
      }                                                                        \
    }                                                                          \
    _Pragma("unroll")                                                          \
    for (int mm = 1; mm < 16; mm <<= 1) {                                      \
      _Pragma("unroll")                                                        \
      for (int r = 0; r < 4; ++r) psum[r] += __shfl_xor(psum[r], mm, 64);      \
    }                                                                          \
    _Pragma("unroll")                                                          \
    for (int r = 0; r < 4; ++r) lsum[r] += psum[r];                            \
    bf16x8 aP[2];                                                              \
    {                                                                          \
      int sw = (lr & 7) << 3;                                                  \
      aP[0] = __builtin_bit_cast(bf16x8, *(const u16x8*)&pl[lr * 64 + ((lg * 8) ^ sw)]);        \
      aP[1] = __builtin_bit_cast(bf16x8, *(const u16x8*)&pl[lr * 64 + ((32 + lg * 8) ^ sw)]);   \
    }                                                                          \
    _Pragma("unroll")                                                          \
    for (int t = 0; t < 4; ++t) {                                              \
      o[t] = __builtin_amdgcn_mfma_f32_16x16x32_bf16(aP[0], bV[t][0], o[t], 0, 0, 0); \
      o[t] = __builtin_amdgcn_mfma_f32_16x16x32_bf16(aP[1], bV[t][1], o[t], 0, 0, 0); \
    }                                                                          \
  }

__global__ __launch_bounds__(256, 4) void attn_mfma(const u16* __restrict__ qb,
                                                    const u16* __restrict__ kb,
                                                    const u16* __restrict__ vtb,
                                                    const float* __restrict__ gates,
                                                    const int* __restrict__ ep,
                                                    u16* __restrict__ outp) {
    __shared__ u16 plds[4][1024];
    __shared__ float o_l[4][16][68];
    __shared__ float ml_l[4][2][16];

    int bid = blockIdx.x;
    int h = bid & 7;                         // XCD-local head
    int q0 = (bid >> 3) * 16;
    int tid = threadIdx.x;
    int w = tid >> 6, lane = tid & 63;
    int lr = lane & 15, lg = lane >> 4;
    u16* pl = plds[w];

    bf16x8 aQ[2];
    {
        const u16* qrow = qb + ((h * NQ + q0 + lr) * DHD + lg * 8);
        aQ[0] = __builtin_bit_cast(bf16x8, *(const u16x8*)qrow);
        aQ[1] = __builtin_bit_cast(bf16x8, *(const u16x8*)(qrow + 32));
    }

    int qpos[4], epq[4];
    float gq[4];
#pragma unroll
    for (int r = 0; r < 4; ++r) {
        int q = q0 + lg * 4 + r;
        qpos[r] = 512 + q;
        epq[r] = ep[512 + q];
        gq[r] = gates[h * NQ + q];
    }

    f32x4 o[4];
    float mrun[4], lsum[4];
#pragma unroll
    for (int t = 0; t < 4; ++t) { f32x4 z = {0.f,0.f,0.f,0.f}; o[t] = z; }
#pragma unroll
    for (int r = 0; r < 4; ++r) { mrun[r] = NEGF; lsum[r] = 0.f; }

    int c_lo = q0 & ~511;
    int nch = (591 + (q0 & 511)) >> 6;       // 9..16 chunks
    int base = nch >> 2, rem = nch & 3;
    int my_n = base + (w < rem ? 1 : 0);
    int pre = w * base + (w < rem ? w : rem);
    int c0 = c_lo + (pre << 6);

    bf16x8 bKA[4][2], bKB[4][2];
    int epA[4], epB[4];

    LOADK(bKA, epA, c0)
    int ci = 0;
    while (true) {
        bool more = (ci + 1 < my_n);
        DO_CHUNK(c0, bKA, epA, more, bKB, epB)
        ++ci; c0 += 64;
        if (!more) break;
        bool more2 = (ci + 1 < my_n);
        DO_CHUNK(c0, bKB, epB, more2, bKA, epA)
        ++ci; c0 += 64;
        if (!more2) break;
    }

    // ---- 4-way (m,l,o) merge ----
    if (lr == 0) {
#pragma unroll
        for (int r = 0; r < 4; ++r) {
            int row = lg * 4 + r;
            ml_l[w][0][row] = mrun[r];
            ml_l[w][1][row] = lsum[r];
        }
    }
    __syncthreads();
    float inv[4];
#pragma unroll
    for (int r = 0; r < 4; ++r) {
        int row = lg * 4 + r;
        float mg = NEGF;
#pragma unroll
        for (int s = 0; s < 4; ++s) mg = fmaxf(mg, ml_l[s][0][row]);
        float lt = 0.f;
#pragma unroll
        for (int s = 0; s < 4; ++s) {
            float ms = ml_l[s][0][row];
            if (ms > -1e29f) lt += ml_l[s][1][row] * __expf(ms - mg);
        }
        float f = (mrun[r] > -1e29f) ? __expf(mrun[r] - mg) : 0.f;
#pragma unroll
        for (int t = 0; t < 4; ++t) o_l[w][row][t * 16 + lr] = o[t][r] * f;
        inv[r] = gq[r] / lt;
    }
    __syncthreads();
#pragma unroll
    for (int r = 0; r < 4; ++r) {
        int row = lg * 4 + r;
        float sum = o_l[0][row][w * 16 + lr] + o_l[1][row][w * 16 + lr]
                  + o_l[2][row][w * 16 + lr] + o_l[3][row][w * 16 + lr];
        outp[(q0 + row) * DMODEL + h * DHD + w * 16 + lr] = f2bf(sum * inv[r]);
    }
}

// ---------------------------------------------------------------------------
// out = attn @ Wot. 1024 blocks of 16x64 tiles; bx = bid&7 (Wot panel / XCD).
// ---------------------------------------------------------------------------
__global__ __launch_bounds__(256, 4) void outgemm(const u16* __restrict__ attnb,
                                                  const u16* __restrict__ Wot,
                                                  float* __restrict__ outf) {
    int bid = blockIdx.x, tid = threadIdx.x;
    int w = tid >> 6, lane = tid & 63;
    int lr = lane & 15, lg = lane >> 4;
    int bx = bid & 7, by = bid >> 3;
    int rowbase = by * 16;
    int colbase = bx * 64 + w * 16;
    f32x4 acc = {0.f,0.f,0.f,0.f};
    const u16* a0 = attnb + (rowbase + lr) * 512 + lg * 8;
    const u16* b0 = Wot + (colbase + lr) * 512 + lg * 8;
#pragma unroll 4
    for (int k0 = 0; k0 < 512; k0 += 32) {
        bf16x8 fa = __builtin_bit_cast(bf16x8, *(const u16x8*)(a0 + k0));
        bf16x8 fb = __builtin_bit_cast(bf16x8, *(const u16x8*)(b0 + k0));
        acc = __builtin_amdgcn_mfma_f32_16x16x32_bf16(fa, fb, acc, 0, 0, 0);
    }
#pragma unroll
    for (int r = 0; r < 4; ++r) {
        int n = rowbase + lg * 4 + r;
        outf[n * DMODEL + colbase + lr] = acc[r];
    }
}

// ---------------------------------------------------------------------------
extern "C" void kernel_launch(void* const* d_in, const int* in_sizes, int n_in,
                              void* d_out, int out_size, void* d_ws, size_t ws_size,
                              hipStream_t stream) {
    const float* x       = (const float*)d_in[0];
    const float* cache_k = (const float*)d_in[1];
    const float* cache_v = (const float*)d_in[2];
    const int*   ep      = (const int*)  d_in[3];
    const float* Wq      = (const float*)d_in[4];
    const float* Wkv     = (const float*)d_in[5];
    const float* Wg      = (const float*)d_in[6];
    const float* Wo      = (const float*)d_in[7];
    float* out = (float*)d_out;

    u16* u = (u16*)d_ws;
    u16* x_bf    = u;                          // 1048576
    u16* Wt      = x_bf + 1048576;             // 786432
    u16* Wot     = Wt + 786432;                // 262144
    u16* q_bf    = Wot + 262144;               // 1048576
    u16* k_bf    = q_bf + 1048576;             // 1310720
    u16* vT      = k_bf + 1310720;             // 1310720
    u16* attn_bf = vT + 1310720;               // 1048576
    float*  gatesw = (float*)(attn_bf + 1048576);   // 16384 f32
    float2* cs     = (float2*)(gatesw + 16384);     // 81920 float2

    prep<<<512, 256, 0, stream>>>(x, Wq, Wkv, Wo, Wg, cache_v, cache_k,
                                  x_bf, Wt, Wot, gatesw, cs, vT, k_bf);
    qkv<<<1536, 256, 0, stream>>>(x_bf, Wt, cs, q_bf, k_bf, vT);
    attn_mfma<<<1024, 256, 0, stream>>>(q_bf, k_bf, vT, gatesw, ep, attn_bf);
    outgemm<<<1024, 256, 0, stream>>>(attn_bf, Wot, out);
}

// Round 11
// 174.316 us; speedup vs baseline: 1.2159x; 1.2159x over previous
//
#include <hip/hip_runtime.h>
#include <math.h>

#define NQ     2048
#define DMODEL 512
#define NH     8
#define DHD    64
#define MEMT   512
#define KVT    2560
#define QSCALE 0.125f
#define NEGF   (-1e30f)

typedef unsigned short u16;
typedef __bf16 bf16x8 __attribute__((ext_vector_type(8)));
typedef float  f32x4  __attribute__((ext_vector_type(4)));
typedef u16    u16x8  __attribute__((ext_vector_type(8)));
typedef u16    u16x4  __attribute__((ext_vector_type(4)));
typedef u16    u16x2  __attribute__((ext_vector_type(2)));

__device__ __forceinline__ u16 f2bf(float f) {
    union { float f; unsigned u; } v; v.f = f;
    unsigned r = (v.u + 0x7FFFu + ((v.u >> 16) & 1u)) >> 16;
    return (u16)r;
}

// ---------------------------------------------------------------------------
// prep: [0,32) x->bf16 | [32,288) W transposes | [288,320) gates
//       [320,384) RoPE table | [384,448) cache-V transpose | [448,512) cache-K RoPE
// ---------------------------------------------------------------------------
__global__ __launch_bounds__(256, 4) void prep(const float* __restrict__ x,
                                               const float* __restrict__ Wq,
                                               const float* __restrict__ Wkv,
                                               const float* __restrict__ Wo,
                                               const float* __restrict__ Wg,
                                               const float* __restrict__ cache_v,
                                               const float* __restrict__ cache_k,
                                               u16* __restrict__ xb,
                                               u16* __restrict__ Wt,
                                               u16* __restrict__ Wot,
                                               float* __restrict__ gates,
                                               float2* __restrict__ cs,
                                               u16* __restrict__ vtb,
                                               u16* __restrict__ kb) {
    __shared__ __attribute__((aligned(16))) char smem[16640];
    int bid = blockIdx.x, tid = threadIdx.x;

    if (bid < 32) {                          // x -> bf16
        int base4 = bid * 8192;
#pragma unroll
        for (int u = 0; u < 32; ++u) {
            int i4 = base4 + u * 256 + tid;
            float4 v = ((const float4*)x)[i4];
            u16x4 o4 = { f2bf(v.x), f2bf(v.y), f2bf(v.z), f2bf(v.w) };
            *(u16x4*)&xb[i4 * 4] = o4;
        }
    } else if (bid < 288) {                  // W transposes
        float (*tile)[65] = (float(*)[65])smem;
        int tt = bid - 32;
        bool isQKV = (tt < 192);
        int tc, tr;
        if (isQKV) { tc = tt % 24; tr = tt / 24; }
        else       { tt -= 192; tc = tt & 7; tr = tt >> 3; }
        int rr = tid >> 4, c4 = (tid & 15) * 4;
#pragma unroll
        for (int u = 0; u < 4; ++u) {
            int row = u * 16 + rr;
            int k = tr * 64 + row, c = tc * 64 + c4;
            float4 v;
            if (isQKV) v = (c < 512) ? *(const float4*)&Wq[k * 512 + c]
                                     : *(const float4*)&Wkv[k * 1024 + (c - 512)];
            else       v = *(const float4*)&Wo[k * 512 + c];
            tile[row][c4 + 0] = v.x; tile[row][c4 + 1] = v.y;
            tile[row][c4 + 2] = v.z; tile[row][c4 + 3] = v.w;
        }
        __syncthreads();
#pragma unroll
        for (int u = 0; u < 4; ++u) {
            int trow = u * 16 + rr;
            u16x4 o4;
#pragma unroll
            for (int i = 0; i < 4; ++i) o4[i] = f2bf(tile[c4 + i][trow]);
            int tg = tc * 64 + trow, kg = tr * 64 + c4;
            if (isQKV) *(u16x4*)&Wt[tg * 512 + kg] = o4;
            else       *(u16x4*)&Wot[tg * 512 + kg] = o4;
        }
    } else if (bid < 320) {                  // gates
#pragma unroll
        for (int kk = 0; kk < 2; ++kk) {
            int t = (bid - 288) * 512 + kk * 256 + tid;
            int n = t >> 3, hh = t & 7;
            float acc = 0.f;
            for (int k = 0; k < DMODEL; k += 4) {
                float4 xv = *(const float4*)&x[n * DMODEL + k];
                acc += xv.x * Wg[(k + 0) * NH + hh] + xv.y * Wg[(k + 1) * NH + hh]
                     + xv.z * Wg[(k + 2) * NH + hh] + xv.w * Wg[(k + 3) * NH + hh];
            }
            gates[hh * NQ + n] = 1.f / (1.f + __expf(-acc));
        }
    } else if (bid < 384) {                  // RoPE cos/sin table (for qkv epilogue)
#pragma unroll
        for (int kk = 0; kk < 5; ++kk) {
            int idx = (bid - 320) * 1280 + kk * 256 + tid;
            int pos = idx >> 5, j = idx & 31;
            float invf = exp2f(-(float)j * (13.287712379549449f / 32.f));
            float ss, sc;
            sincosf((float)pos * invf, &ss, &sc);
            cs[idx] = make_float2(sc, ss);
        }
    } else if (bid < 448) {                  // cache-V transpose -> vtb rows [0,512)
        u16 (*tile)[66] = (u16(*)[66])smem;
        int uu = bid - 384;
        int tb = uu & 7, h = uu >> 3;
        int rr = tid >> 4, c4 = (tid & 15) * 4;
        int r0 = tb * 64;
#pragma unroll
        for (int u = 0; u < 4; ++u) {
            int row = u * 16 + rr;
            float4 v = *(const float4*)&cache_v[(h * MEMT + r0 + row) * DHD + c4];
            tile[row][c4 + 0] = f2bf(v.x); tile[row][c4 + 1] = f2bf(v.y);
            tile[row][c4 + 2] = f2bf(v.z); tile[row][c4 + 3] = f2bf(v.w);
        }
        __syncthreads();
#pragma unroll
        for (int u = 0; u < 4; ++u) {
            int d = u * 16 + rr;
            u16x4 o4 = { tile[c4 + 0][d], tile[c4 + 1][d], tile[c4 + 2][d], tile[c4 + 3][d] };
            *(u16x4*)&vtb[(h * DHD + d) * KVT + r0 + c4] = o4;
        }
    } else {                                 // cache-K RoPE (inline sincos) -> kb [0,512)
        int uu = bid - 448;
        int r0 = (uu & 7) * 64, h = uu >> 3;
        int j = tid & 31;
        float invf = exp2f(-(float)j * (13.287712379549449f / 32.f));
#pragma unroll
        for (int u = 0; u < 8; ++u) {
            int idx = u * 256 + tid;
            int row = idx >> 5;
            int r = r0 + row;
            float a = cache_k[(h * MEMT + r) * DHD + j];
            float b = cache_k[(h * MEMT + r) * DHD + 32 + j];
            float ss, sc;
            sincosf((float)r * invf, &ss, &sc);
            kb[(h * KVT + r) * DHD + j]      = f2bf(a * sc - b * ss);
            kb[(h * KVT + r) * DHD + 32 + j] = f2bf(b * sc + a * ss);
        }
    }
}

// ---------------------------------------------------------------------------
// qkv: 1536 blocks, one 32x64 tile each (XCD-swizzled: xcd owns 3 col-panels).
// Epilogue: RoPE (q/k) via cs table, V transposed via LDS into vtb.
// ---------------------------------------------------------------------------
__global__ __launch_bounds__(256, 4) void qkv(const u16* __restrict__ xb,
                                              const u16* __restrict__ Wt,
                                              const float2* __restrict__ cs,
                                              u16* __restrict__ qb,
                                              u16* __restrict__ kb,
                                              u16* __restrict__ vtb) {
    __shared__ __attribute__((aligned(16))) u16 vtile[32][66];
    const int bid = blockIdx.x, tid = threadIdx.x;
    const int w = tid >> 6, lane = tid & 63;
    const int lr = lane & 15, lg = lane >> 4;

    int i = bid >> 3;                        // 0..191
    int sub = i % 3, byr = i / 3;            // col-in-triple, row tile 0..63
    int bx = (bid & 7) * 3 + sub;            // col panel 0..23, XCD-local triple
    int rowbase = byr * 32;
    int rfrag = rowbase + (w >> 1) * 16;
    int colbase = bx * 64 + (w & 1) * 16;

    f32x4 acc0 = {0.f,0.f,0.f,0.f}, acc1 = {0.f,0.f,0.f,0.f};
    const u16* a0 = xb + (rfrag + lr) * 512 + lg * 8;
    const u16* b0 = Wt + (colbase + lr) * 512 + lg * 8;
    const u16* b1 = b0 + 32 * 512;
#pragma unroll 4
    for (int k0 = 0; k0 < 512; k0 += 32) {
        bf16x8 fa  = __builtin_bit_cast(bf16x8, *(const u16x8*)(a0 + k0));
        bf16x8 fb0 = __builtin_bit_cast(bf16x8, *(const u16x8*)(b0 + k0));
        bf16x8 fb1 = __builtin_bit_cast(bf16x8, *(const u16x8*)(b1 + k0));
        acc0 = __builtin_amdgcn_mfma_f32_16x16x32_bf16(fa, fb0, acc0, 0, 0, 0);
        acc1 = __builtin_amdgcn_mfma_f32_16x16x32_bf16(fa, fb1, acc1, 0, 0, 0);
    }

    int j = (colbase & 63) + lr;             // 0..31
    int region = bx >> 3;                    // 0=q, 1=k_new, 2=v
    int h = bx & 7;
    if (region == 2) {
        __syncthreads();
#pragma unroll
        for (int r = 0; r < 4; ++r) {
            int rl = (w >> 1) * 16 + lg * 4 + r;
            vtile[rl][j]      = f2bf(acc0[r]);
            vtile[rl][j + 32] = f2bf(acc1[r]);
        }
        __syncthreads();
        int rr = tid >> 4, c2 = (tid & 15) * 2;
#pragma unroll
        for (int u = 0; u < 4; ++u) {
            int d = u * 16 + rr;
            u16x2 o2 = { vtile[c2][d], vtile[c2 + 1][d] };
            *(u16x2*)&vtb[(h * DHD + d) * KVT + 512 + rowbase + c2] = o2;
        }
    } else {
#pragma unroll
        for (int r = 0; r < 4; ++r) {
            int n = rfrag + lg * 4 + r;
            float a = acc0[r], b = acc1[r];
            float2 csv = cs[(512 + n) * 32 + j];
            u16 e0 = f2bf(a * csv.x - b * csv.y);
            u16 e1 = f2bf(b * csv.x + a * csv.y);
            if (region == 0) {
                qb[(h * NQ + n) * DHD + j]      = e0;
                qb[(h * NQ + n) * DHD + 32 + j] = e1;
            } else {
                kb[(h * KVT + 512 + n) * DHD + j]      = e0;
                kb[(h * KVT + 512 + n) * DHD + 32 + j] = e1;
            }
        }
    }
}

// ---------------------------------------------------------------------------
// attn: 1024 blocks = (head = bid&7, 16-query tile = bid>>3). 4 waves each own
// a quarter of the KV chunks (online softmax per wave), 4-way merge via LDS.
// launch_bounds(256,2): VGPR cap 256 -> K-prefetch double-buffer fits, NO spill
// (round 10's (256,4) forced VGPR<=128 -> scratch thrash: WRITE_SIZE 129 MB).
// ---------------------------------------------------------------------------
#define LOADK(BK, BEP, C0)                                                     \
  _Pragma("unroll")                                                            \
  for (int t = 0; t < 4; ++t) {                                                \
    const u16* kr = kb + ((h * KVT + (C0) + t * 16 + lr) * DHD + lg * 8);      \
    BK[t][0] = __builtin_bit_cast(bf16x8, *(const u16x8*)kr);                  \
    BK[t][1] = __builtin_bit_cast(bf16x8, *(const u16x8*)(kr + 32));           \
    BEP[t] = ep[(C0) + t * 16 + lr];                                           \
  }

#define DO_CHUNK(C0, BK, BEP, PREF, NBK, NBEP)                                 \
  {                                                                            \
    bf16x8 bV[4][2];                                                           \
    _Pragma("unroll")                                                          \
    for (int t = 0; t < 4; ++t) {                                              \
      const u16* vr = vtb + ((h * DHD + t * 16 + lr) * KVT + (C0) + lg * 8);   \
      bV[t][0] = __builtin_bit_cast(bf16x8, *(const u16x8*)vr);                \
      bV[t][1] = __builtin_bit_cast(bf16x8, *(const u16x8*)(vr + 32));         \
    }                                                                          \
    f32x4 s[4];                                                                \
    _Pragma("unroll")                                                          \
    for (int t = 0; t < 4; ++t) {                                              \
      f32x4 z = {0.f, 0.f, 0.f, 0.f};                                          \
      s[t] = __builtin_amdgcn_mfma_f32_16x16x32_bf16(aQ[0], BK[t][0], z, 0, 0, 0); \
      s[t] = __builtin_amdgcn_mfma_f32_16x16x32_bf16(aQ[1], BK[t][1], s[t], 0, 0, 0); \
    }                                                                          \
    if (PREF) { LOADK(NBK, NBEP, (C0) + 64) }                                  \
    float rmax[4] = {NEGF, NEGF, NEGF, NEGF};                                  \
    _Pragma("unroll")                                                          \
    for (int t = 0; t < 4; ++t) {                                              \
      int key = (C0) + t * 16 + lr;                                            \
      int ek = BEP[t];                                                         \
      _Pragma("unroll")                                                        \
      for (int r = 0; r < 4; ++r) {                                            \
        bool vld = (key <= qpos[r]) && (ek == epq[r]);                         \
        float sv = vld ? s[t][r] * QSCALE : NEGF;                              \
        s[t][r] = sv;                                                          \
        rmax[r] = fmaxf(rmax[r], sv);                                          \
      }                                                                        \
    }                                                                          \
    _Pragma("unroll")                                                          \
    for (int mm = 1; mm < 16; mm <<= 1) {                                      \
      _Pragma("unroll")                                                        \
      for (int r = 0; r < 4; ++r)                                              \
        rmax[r] = fmaxf(rmax[r], __shfl_xor(rmax[r], mm, 64));                 \
    }                                                                          \
    float alpha[4];                                                            \
    _Pragma("unroll")                                                          \
    for (int r = 0; r < 4; ++r) {                                              \
      float mn = fmaxf(mrun[r], rmax[r]);                                      \
      alpha[r] = __expf(mrun[r] - mn);                                         \
      mrun[r] = mn;                                                            \
      lsum[r] *= alpha[r];                                                     \
    }                                                                          \
    _Pragma("unroll")                                                          \
    for (int t = 0; t < 4; ++t)                                                \
      _Pragma("unroll")                                                        \
      for (int r = 0; r < 4; ++r) o[t][r] *= alpha[r];                         \
    float psum[4] = {0.f, 0.f, 0.f, 0.f};                                      \
    _Pragma("unroll")                                                          \
    for (int t = 0; t < 4; ++t) {                                              \
      _Pragma("unroll")                                                        \
      for (int r = 0; r < 4; ++r) {                                            \
        float sv = s[t][r];                                                    \
        float p = (sv <= -1e29f) ? 0.f : __expf(sv - mrun[r]);                 \
        psum[r] += p;                                                          \
        int qq = lg * 4 + r;                                                   \
        int kk2 = t * 16 + lr;                                                 \
        pl[qq * 64 + (kk2 ^ ((qq & 7) << 3))] = f2bf(p);                       \
      }                                                                        \
    }                                                                          \
    _Pragma("unroll")                                                          \
    for (int mm = 1; mm < 16; mm <<= 1) {                                      \
      _Pragma("unroll")                                                        \
      for (int r = 0; r < 4; ++r) psum[r] += __shfl_xor(psum[r], mm, 64);      \
    }                                                                          \
    _Pragma("unroll")                                                          \
    for (int r = 0; r < 4; ++r) lsum[r] += psum[r];                            \
    bf16x8 aP[2];                                                              \
    {                                                                          \
      int sw = (lr & 7) << 3;                                                  \
      aP[0] = __builtin_bit_cast(bf16x8, *(const u16x8*)&pl[lr * 64 + ((lg * 8) ^ sw)]);        \
      aP[1] = __builtin_bit_cast(bf16x8, *(const u16x8*)&pl[lr * 64 + ((32 + lg * 8) ^ sw)]);   \
    }                                                                          \
    _Pragma("unroll")                                                          \
    for (int t = 0; t < 4; ++t) {                                              \
      o[t] = __builtin_amdgcn_mfma_f32_16x16x32_bf16(aP[0], bV[t][0], o[t], 0, 0, 0); \
      o[t] = __builtin_amdgcn_mfma_f32_16x16x32_bf16(aP[1], bV[t][1], o[t], 0, 0, 0); \
    }                                                                          \
  }

__global__ __launch_bounds__(256, 2) void attn_mfma(const u16* __restrict__ qb,
                                                    const u16* __restrict__ kb,
                                                    const u16* __restrict__ vtb,
                                                    const float* __restrict__ gates,
                                                    const int* __restrict__ ep,
                                                    u16* __restrict__ outp) {
    __shared__ u16 plds[4][1024];
    __shared__ float o_l[4][16][68];
    __shared__ float ml_l[4][2][16];

    int bid = blockIdx.x;
    int h = bid & 7;                         // XCD-local head
    int q0 = (bid >> 3) * 16;
    int tid = threadIdx.x;
    int w = tid >> 6, lane = tid & 63;
    int lr = lane & 15, lg = lane >> 4;
    u16* pl = plds[w];

    bf16x8 aQ[2];
    {
        const u16* qrow = qb + ((h * NQ + q0 + lr) * DHD + lg * 8);
        aQ[0] = __builtin_bit_cast(bf16x8, *(const u16x8*)qrow);
        aQ[1] = __builtin_bit_cast(bf16x8, *(const u16x8*)(qrow + 32));
    }

    int qpos[4], epq[4];
    float gq[4];
#pragma unroll
    for (int r = 0; r < 4; ++r) {
        int q = q0 + lg * 4 + r;
        qpos[r] = 512 + q;
        epq[r] = ep[512 + q];
        gq[r] = gates[h * NQ + q];
    }

    f32x4 o[4];
    float mrun[4], lsum[4];
#pragma unroll
    for (int t = 0; t < 4; ++t) { f32x4 z = {0.f,0.f,0.f,0.f}; o[t] = z; }
#pragma unroll
    for (int r = 0; r < 4; ++r) { mrun[r] = NEGF; lsum[r] = 0.f; }

    int c_lo = q0 & ~511;
    int nch = (591 + (q0 & 511)) >> 6;       // 9..16 chunks
    int base = nch >> 2, rem = nch & 3;
    int my_n = base + (w < rem ? 1 : 0);
    int pre = w * base + (w < rem ? w : rem);
    int c0 = c_lo + (pre << 6);

    bf16x8 bKA[4][2], bKB[4][2];
    int epA[4], epB[4];

    LOADK(bKA, epA, c0)
    int ci = 0;
    while (true) {
        bool more = (ci + 1 < my_n);
        DO_CHUNK(c0, bKA, epA, more, bKB, epB)
        ++ci; c0 += 64;
        if (!more) break;
        bool more2 = (ci + 1 < my_n);
        DO_CHUNK(c0, bKB, epB, more2, bKA, epA)
        ++ci; c0 += 64;
        if (!more2) break;
    }

    // ---- 4-way (m,l,o) merge ----
    if (lr == 0) {
#pragma unroll
        for (int r = 0; r < 4; ++r) {
            int row = lg * 4 + r;
            ml_l[w][0][row] = mrun[r];
            ml_l[w][1][row] = lsum[r];
        }
    }
    __syncthreads();
    float inv[4];
#pragma unroll
    for (int r = 0; r < 4; ++r) {
        int row = lg * 4 + r;
        float mg = NEGF;
#pragma unroll
        for (int s = 0; s < 4; ++s) mg = fmaxf(mg, ml_l[s][0][row]);
        float lt = 0.f;
#pragma unroll
        for (int s = 0; s < 4; ++s) {
            float ms = ml_l[s][0][row];
            if (ms > -1e29f) lt += ml_l[s][1][row] * __expf(ms - mg);
        }
        float f = (mrun[r] > -1e29f) ? __expf(mrun[r] - mg) : 0.f;
#pragma unroll
        for (int t = 0; t < 4; ++t) o_l[w][row][t * 16 + lr] = o[t][r] * f;
        inv[r] = gq[r] / lt;
    }
    __syncthreads();
#pragma unroll
    for (int r = 0; r < 4; ++r) {
        int row = lg * 4 + r;
        float sum = o_l[0][row][w * 16 + lr] + o_l[1][row][w * 16 + lr]
                  + o_l[2][row][w * 16 + lr] + o_l[3][row][w * 16 + lr];
        outp[(q0 + row) * DMODEL + h * DHD + w * 16 + lr] = f2bf(sum * inv[r]);
    }
}

// ---------------------------------------------------------------------------
// out = attn @ Wot. 1024 blocks of 16x64 tiles; bx = bid&7 (Wot panel / XCD).
// ---------------------------------------------------------------------------
__global__ __launch_bounds__(256, 4) void outgemm(const u16* __restrict__ attnb,
                                                  const u16* __restrict__ Wot,
                                                  float* __restrict__ outf) {
    int bid = blockIdx.x, tid = threadIdx.x;
    int w = tid >> 6, lane = tid & 63;
    int lr = lane & 15, lg = lane >> 4;
    int bx = bid & 7, by = bid >> 3;
    int rowbase = by * 16;
    int colbase = bx * 64 + w * 16;
    f32x4 acc = {0.f,0.f,0.f,0.f};
    const u16* a0 = attnb + (rowbase + lr) * 512 + lg * 8;
    const u16* b0 = Wot + (colbase + lr) * 512 + lg * 8;
#pragma unroll 4
    for (int k0 = 0; k0 < 512; k0 += 32) {
        bf16x8 fa = __builtin_bit_cast(bf16x8, *(const u16x8*)(a0 + k0));
        bf16x8 fb = __builtin_bit_cast(bf16x8, *(const u16x8*)(b0 + k0));
        acc = __builtin_amdgcn_mfma_f32_16x16x32_bf16(fa, fb, acc, 0, 0, 0);
    }
#pragma unroll
    for (int r = 0; r < 4; ++r) {
        int n = rowbase + lg * 4 + r;
        outf[n * DMODEL + colbase + lr] = acc[r];
    }
}

// ---------------------------------------------------------------------------
extern "C" void kernel_launch(void* const* d_in, const int* in_sizes, int n_in,
                              void* d_out, int out_size, void* d_ws, size_t ws_size,
                              hipStream_t stream) {
    const float* x       = (const float*)d_in[0];
    const float* cache_k = (const float*)d_in[1];
    const float* cache_v = (const float*)d_in[2];
    const int*   ep      = (const int*)  d_in[3];
    const float* Wq      = (const float*)d_in[4];
    const float* Wkv     = (const float*)d_in[5];
    const float* Wg      = (const float*)d_in[6];
    const float* Wo      = (const float*)d_in[7];
    float* out = (float*)d_out;

    u16* u = (u16*)d_ws;
    u16* x_bf    = u;                          // 1048576
    u16* Wt      = x_bf + 1048576;             // 786432
    u16* Wot     = Wt + 786432;                // 262144
    u16* q_bf    = Wot + 262144;               // 1048576
    u16* k_bf    = q_bf + 1048576;             // 1310720
    u16* vT      = k_bf + 1310720;             // 1310720
    u16* attn_bf = vT + 1310720;               // 1048576
    float*  gatesw = (float*)(attn_bf + 1048576);   // 16384 f32
    float2* cs     = (float2*)(gatesw + 16384);     // 81920 float2

    prep<<<512, 256, 0, stream>>>(x, Wq, Wkv, Wo, Wg, cache_v, cache_k,
                                  x_bf, Wt, Wot, gatesw, cs, vT, k_bf);
    qkv<<<1536, 256, 0, stream>>>(x_bf, Wt, cs, q_bf, k_bf, vT);
    attn_mfma<<<1024, 256, 0, stream>>>(q_bf, k_bf, vT, gatesw, ep, attn_bf);
    outgemm<<<1024, 256, 0, stream>>>(attn_bf, Wot, out);
}